// Round 8
// baseline (247.579 us; speedup 1.0000x reference)
//
#include <hip/hip_runtime.h>
#include <cstddef>
#include <cstdint>

#define B_ 4
#define C_ 256
#define N_ 4096
/* workspace:
   qf  [b][256 ntile][64 lane][8] bf16   @ 0        (1 MB)
   kf  [b][256 ntile][64 lane][8] bf16   @ 1 MB
   df  [b][16 ctile][128 chunk][64 lane][8] bf16 @ 2 MB (8 MB)
   sums/sumsq/sc/bi (1280 f)             @ 10 MB
   mpart/lpart [4][16384] f              @ +5120
   wf hi/lo frag [20][8][64][8] bf16     @ after                     */
#define KF_OFF_B  ((size_t)1 << 20)
#define DF_OFF_B  ((size_t)2 << 20)
#define SUM_OFF_B ((size_t)10 << 20)
#define ML_OFF_B  (SUM_OFF_B + 5120)
#define WFH_OFF_B (ML_OFF_B + 524288)
#define WFL_OFF_B (WFH_OFF_B + 163840)
#define LOG2E 1.4426950408889634f

typedef unsigned short bfraw;
typedef __attribute__((ext_vector_type(8))) short short8;
typedef __attribute__((ext_vector_type(4))) float float4v;
typedef __attribute__((ext_vector_type(4))) bfraw bfraw4;

__device__ inline bfraw f2bf(float f) {
    union { float f; uint32_t u; } c; c.f = f;
    uint32_t u = c.u;
    u += 0x7fffu + ((u >> 16) & 1u);     // RNE
    return (bfraw)(u >> 16);
}
__device__ inline float bf2f(bfraw h) {
    union { uint32_t u; float f; } c; c.u = ((uint32_t)h) << 16;
    return c.f;
}
#if __has_builtin(__builtin_amdgcn_exp2f)
__device__ inline float EXP2(float x) { return __builtin_amdgcn_exp2f(x); }
#else
__device__ inline float EXP2(float x) { return exp2f(x); }
#endif
__device__ inline uint32_t pack2(float a, float b) {
    union { float f; uint32_t u; } ca, cb; ca.f = a; cb.f = b;
#if __has_builtin(__builtin_amdgcn_perm)
    return __builtin_amdgcn_perm(cb.u + 0x8000u, ca.u + 0x8000u, 0x07060302u);
#else
    return ((ca.u + 0x8000u) >> 16) | ((cb.u + 0x8000u) & 0xffff0000u);
#endif
}

// ---------------------------------------------------------------------------
// wsplit: w -> bf16 hi/lo in A-FRAG layout [ctile][kstep][lane][8];
// block 0 also zeroes the stats accumulators.
// ---------------------------------------------------------------------------
__global__ __launch_bounds__(256) void wsplit_kernel(
    const float* __restrict__ w1, const float* __restrict__ w2,
    const float* __restrict__ w3, uint8_t* __restrict__ wsb)
{
    bfraw* wfh = (bfraw*)(wsb + WFH_OFF_B);
    bfraw* wfl = (bfraw*)(wsb + WFL_OFF_B);
    float* sums = (float*)(wsb + SUM_OFF_B);
    if (blockIdx.x == 0)
        for (int i = threadIdx.x; i < 640; i += 256) sums[i] = 0.f;
    int idx = blockIdx.x * 256 + threadIdx.x;    // grid 320 -> 81920
    int ch = idx >> 8, k = idx & 255;
    const float* wr = (ch < 32) ? (w1 + ch * C_)
                      : (ch < 64) ? (w2 + (ch - 32) * C_)
                                  : (w3 + (ch - 64) * C_);
    float v = wr[k];
    bfraw h = f2bf(v);
    bfraw lo = f2bf(v - bf2f(h));
    int off = (((ch >> 4) * 8 + (k >> 5)) * 64
               + ((ch & 15) | (((k >> 3) & 3) << 4))) * 8 + (k & 7);
    wfh[off] = h;
    wfl[off] = lo;
}

// ---------------------------------------------------------------------------
// out = x  (flash k-split blocks add partial O atomically).
// ---------------------------------------------------------------------------
__global__ __launch_bounds__(256) void initout_kernel(
    const float* __restrict__ x, float* __restrict__ out) {
    size_t i = ((size_t)blockIdx.x * 256 + threadIdx.x) * 4;
    *(float4*)&out[i] = *(const float4*)&x[i];
}

// ---------------------------------------------------------------------------
// ygemm: y = w@x via 3-term bf16 split; x read ONCE (fp32), transposed+split
// into LDS (group-XOR swizzle -> aligned b128 frag reads); w frags from
// global (coalesced, frag layout).  Block = 320ch x 32n, wave w owns ctiles
// w*5..w*5+4.  Grid 512 = 4b x 128 ntiles, 2 blocks/CU.
// Epilogue: per-channel sum/sumsq atomics; qf/kf/df frag-layout stores.
// ---------------------------------------------------------------------------
__global__ __launch_bounds__(256, 2) void ygemm_kernel(
    const float* __restrict__ x, uint8_t* __restrict__ wsb)
{
    __shared__ bfraw Lh[32 * 256];
    __shared__ bfraw Ll[32 * 256];
    const bfraw* wfh = (const bfraw*)(wsb + WFH_OFF_B);
    const bfraw* wfl = (const bfraw*)(wsb + WFL_OFF_B);
    bfraw* qf  = (bfraw*)wsb;
    bfraw* kfp = (bfraw*)(wsb + KF_OFF_B);
    bfraw* dfp = (bfraw*)(wsb + DF_OFF_B);
    float* sums  = (float*)(wsb + SUM_OFF_B);
    float* sumsq = sums + 320;

    const int bid = blockIdx.x;
    const int b  = bid >> 7;
    const int n0 = (bid & 127) << 5;
    const int t = threadIdx.x, w = t >> 6, l = t & 63, lq = l & 15, lg = l >> 4;

    // ---- stage x[256c][32n] -> LDS [n][c] bf16 hi/lo, swizzled groups ----
    {
        const int cr = t >> 3;
        const int nl = (t & 7) << 2;
        for (int p = 0; p < 8; ++p) {
            int c = p * 32 + cr;
            float4 v = *(const float4*)&x[((size_t)b * C_ + c) * N_ + n0 + nl];
            float va[4] = {v.x, v.y, v.z, v.w};
#pragma unroll
            for (int j = 0; j < 4; ++j) {
                int n = nl + j;
                bfraw h = f2bf(va[j]);
                bfraw lo = f2bf(va[j] - bf2f(h));
                int addr = n * 256 + ((((c >> 3) ^ (n & 7)) << 3) | (c & 7));
                Lh[addr] = h;
                Ll[addr] = lo;
            }
        }
    }
    __syncthreads();

    float4v acc[5][2];
#pragma unroll
    for (int i = 0; i < 5; ++i)
#pragma unroll
        for (int j = 0; j < 2; ++j) acc[i][j] = (float4v){0.f, 0.f, 0.f, 0.f};

    for (int s = 0; s < 8; ++s) {
        short8 ah[5], al[5], bh[2], bl[2];
#pragma unroll
        for (int i = 0; i < 5; ++i) {
            size_t woff = ((size_t)((w * 5 + i) * 8 + s) * 64 + l) * 8;
            ah[i] = *(const short8*)&wfh[woff];
            al[i] = *(const short8*)&wfl[woff];
        }
#pragma unroll
        for (int nt = 0; nt < 2; ++nt) {
            int n = nt * 16 + lq;
            int G = s * 4 + lg;
            int a = n * 256 + ((G ^ (n & 7)) << 3);
            bh[nt] = *(const short8*)&Lh[a];
            bl[nt] = *(const short8*)&Ll[a];
        }
#pragma unroll
        for (int i = 0; i < 5; ++i)
#pragma unroll
            for (int nt = 0; nt < 2; ++nt) {
                acc[i][nt] = __builtin_amdgcn_mfma_f32_16x16x32_bf16(ah[i], bh[nt], acc[i][nt], 0, 0, 0);
                acc[i][nt] = __builtin_amdgcn_mfma_f32_16x16x32_bf16(al[i], bh[nt], acc[i][nt], 0, 0, 0);
                acc[i][nt] = __builtin_amdgcn_mfma_f32_16x16x32_bf16(ah[i], bl[nt], acc[i][nt], 0, 0, 0);
            }
    }

#pragma unroll
    for (int i = 0; i < 5; ++i) {
        const int ctg = w * 5 + i;
        // stats: reduce over this block's 32 n
#pragma unroll
        for (int r = 0; r < 4; ++r) {
            float a0 = acc[i][0][r], a1 = acc[i][1][r];
            float sv = a0 + a1;
            float qv = a0 * a0 + a1 * a1;
#pragma unroll
            for (int m = 1; m < 16; m <<= 1) {
                sv += __shfl_xor(sv, m);
                qv += __shfl_xor(qv, m);
            }
            if (lq == 0) {
                atomicAdd(&sums[ctg * 16 + lg * 4 + r], sv);
                atomicAdd(&sumsq[ctg * 16 + lg * 4 + r], qv);
            }
        }
        // stores (region is uniform per ctg: 2 tiles per 32-ch region)
#pragma unroll
        for (int nt = 0; nt < 2; ++nt)
#pragma unroll
            for (int r = 0; r < 4; ++r) {
                int ch = ctg * 16 + lg * 4 + r;
                int n = n0 + nt * 16 + lq;
                bfraw v = f2bf(acc[i][nt][r]);
                if (ch < 32) {
                    qf[((size_t)(b * 256 + (n >> 4))) * 512
                       + (((n & 15) | (((ch >> 3) & 3) << 4)) << 3) + (ch & 7)] = v;
                } else if (ch < 64) {
                    int c2 = ch - 32;
                    kfp[((size_t)(b * 256 + (n >> 4))) * 512
                        + (((n & 15) | (((c2 >> 3) & 3) << 4)) << 3) + (c2 & 7)] = v;
                } else {
                    int cg = ch - 64;
                    dfp[(((size_t)(b * 16 + (cg >> 4))) * 128 + (n >> 5)) * 512
                        + (((cg & 15) | (((n >> 3) & 3) << 4)) << 3) + (n & 7)] = v;
                }
            }
    }
}

// ---------------------------------------------------------------------------
// finalize BN -> folded scale/bias; q channels pre-scaled by log2(e).
// ---------------------------------------------------------------------------
__global__ void finalize_kernel(
    const float* __restrict__ g1, const float* __restrict__ b1,
    const float* __restrict__ g2, const float* __restrict__ b2,
    const float* __restrict__ g3, const float* __restrict__ b3,
    float* __restrict__ sums)
{
    int ch = threadIdx.x;
    if (ch >= 320) return;
    const float inv = 1.0f / (float)(B_ * N_);
    float mean = sums[ch] * inv;
    float var = sums[320 + ch] * inv - mean * mean;
    float g, bb;
    if (ch < 32)      { g = g1[ch];      bb = b1[ch]; }
    else if (ch < 64) { g = g2[ch - 32]; bb = b2[ch - 32]; }
    else              { g = g3[ch - 64]; bb = b3[ch - 64]; }
    float sc = g * rsqrtf(var + 1e-5f);
    float bi = bb - sc * mean;
    if (ch < 32) { sc *= LOG2E; bi *= LOG2E; }
    sums[640 + ch] = sc;
    sums[960 + ch] = bi;
}

// ---------------------------------------------------------------------------
// in-place bf16 relu(sc*y + bi) over frag-layout planes.
// ---------------------------------------------------------------------------
__global__ __launch_bounds__(256) void affine_kernel(uint8_t* __restrict__ wsb)
{
    bfraw* base = (bfraw*)wsb;
    const float* sc = (const float*)(wsb + SUM_OFF_B) + 640;
    const float* bi = sc + 320;
    size_t i8 = ((size_t)blockIdx.x * 256 + threadIdx.x) * 8;
    bfraw4 v0 = *(bfraw4*)&base[i8];
    bfraw4 v1 = *(bfraw4*)&base[i8 + 4];
    if (i8 < 1048576) {                          // qf or kf
        int ch0 = (((int)(i8 >> 7)) & 3) * 8 + ((i8 < 524288) ? 0 : 32);
        float4 s0 = *(const float4*)&sc[ch0];
        float4 s1 = *(const float4*)&sc[ch0 + 4];
        float4 c0 = *(const float4*)&bi[ch0];
        float4 c1 = *(const float4*)&bi[ch0 + 4];
        float sa[8] = {s0.x, s0.y, s0.z, s0.w, s1.x, s1.y, s1.z, s1.w};
        float ca[8] = {c0.x, c0.y, c0.z, c0.w, c1.x, c1.y, c1.z, c1.w};
#pragma unroll
        for (int j = 0; j < 4; ++j) {
            v0[j] = f2bf(fmaxf(0.f, fmaf(sa[j],     bf2f(v0[j]), ca[j])));
            v1[j] = f2bf(fmaxf(0.f, fmaf(sa[j + 4], bf2f(v1[j]), ca[j + 4])));
        }
    } else {                                     // df
        size_t rel = i8 - 1048576;
        int ch = 64 + (((int)(rel >> 16)) & 15) * 16 + (((int)(rel >> 3)) & 15);
        float s = sc[ch], b = bi[ch];
#pragma unroll
        for (int j = 0; j < 4; ++j) {
            v0[j] = f2bf(fmaxf(0.f, fmaf(s, bf2f(v0[j]), b)));
            v1[j] = f2bf(fmaxf(0.f, fmaf(s, bf2f(v1[j]), b)));
        }
    }
    *(bfraw4*)&base[i8] = v0;
    *(bfraw4*)&base[i8 + 4] = v1;
}

// ---------------------------------------------------------------------------
// softmax stats, k-split x4.  (exp once per (q,k) per split; log2 domain.)
// ---------------------------------------------------------------------------
__global__ __launch_bounds__(256, 4) void mlpass_kernel(uint8_t* __restrict__ wsb)
{
    const bfraw* qf  = (const bfraw*)wsb;
    const bfraw* kfp = (const bfraw*)(wsb + KF_OFF_B);
    float* mpart = (float*)(wsb + ML_OFF_B);
    float* lpart = mpart + 65536;
    const int id = blockIdx.x;
    const int b = id & 3;
    const int ks = (id >> 2) & 3;
    const int n0q = (id >> 4) << 6;
    const int tid = threadIdx.x;
    const int w = tid >> 6, l = tid & 63, lq = l & 15, lg = l >> 4;
    const short8 qfrag = *(const short8*)&qf[((size_t)(b * 256 + (n0q >> 4) + w)) * 512 + l * 8];

    float mx = -1e30f, sum = 0.f;
    const int tbeg = b * 256 + ks * 64;
    for (int tk = tbeg; tk < tbeg + 64; tk += 8) {
        float4v st[8];
#pragma unroll
        for (int kt = 0; kt < 8; ++kt) {
            short8 kf = *(const short8*)&kfp[((size_t)(tk + kt)) * 512 + l * 8];
            float4v z = {0.f, 0.f, 0.f, 0.f};
            st[kt] = __builtin_amdgcn_mfma_f32_16x16x32_bf16(kf, qfrag, z, 0, 0, 0);
        }
        float m1 = st[0][0];
#pragma unroll
        for (int kt = 0; kt < 8; ++kt)
#pragma unroll
            for (int r = 0; r < 4; ++r) m1 = fmaxf(m1, st[kt][r]);
        float nm = fmaxf(mx, m1);
        float ae = 0.f;
#pragma unroll
        for (int kt = 0; kt < 8; ++kt)
#pragma unroll
            for (int r = 0; r < 4; ++r) ae += EXP2(st[kt][r] - nm);
        sum = sum * EXP2(mx - nm) + ae;
        mx = nm;
    }
#pragma unroll
    for (int m = 16; m < 64; m <<= 1) {
        float mo = __shfl_xor(mx, m);
        float so = __shfl_xor(sum, m);
        float nm = fmaxf(mx, mo);
        sum = sum * EXP2(mx - nm) + so * EXP2(mo - nm);
        mx = nm;
    }
    if (lg == 0) {
        int idx = ks * 16384 + b * N_ + n0q + w * 16 + lq;
        mpart[idx] = mx;
        lpart[idx] = sum;
    }
}

// ---------------------------------------------------------------------------
// PV flash: TQ=64, in-block c-split (wave w: scores for q-tile w; PV for
// ctiles {w, w+4, w+8, w+12} x 4 q-tiles), k-split x2 (atomics into out=x).
// exp ONCE per (q,k); -mlq folded into score MFMA C-init.  Grid 512:
// XCD = id&7 -> b = (id&7)>>1 (2 XCDs per batch, L2-resident operands),
// kh = id&1, q-block = id>>3.
// ---------------------------------------------------------------------------
__global__ __launch_bounds__(256, 2) void flash_kernel(
    const uint8_t* __restrict__ wsb, float* __restrict__ out)
{
    const bfraw* qf  = (const bfraw*)wsb;
    const bfraw* kfp = (const bfraw*)(wsb + KF_OFF_B);
    const bfraw* dfp = (const bfraw*)(wsb + DF_OFF_B);
    const float* mpart = (const float*)(wsb + ML_OFF_B);
    const float* lpart = mpart + 65536;
    __shared__ bfraw Pl[2][64 * 128];            // 32 KB dbuf

    const int id  = blockIdx.x;
    const int b   = (id & 7) >> 1;
    const int kh  = id & 1;
    const int n0q = (id >> 3) << 6;
    const int tid = threadIdx.x;
    const int w   = tid >> 6;
    const int l   = tid & 63;
    const int lq  = l & 15;
    const int lg  = l >> 4;
    const int sw  = lq & 7;

    const short8 qfrag = *(const short8*)&qf[((size_t)(b * 256 + (n0q >> 4) + w)) * 512 + l * 8];
    float mlq;
    {
        int qi = b * N_ + n0q + w * 16 + lq;
        float M = -1e30f, ms[4], ls[4];
#pragma unroll
        for (int s = 0; s < 4; ++s) {
            ms[s] = mpart[s * 16384 + qi];
            ls[s] = lpart[s * 16384 + qi];
            M = fmaxf(M, ms[s]);
        }
        float L = 0.f;
#pragma unroll
        for (int s = 0; s < 4; ++s) L += ls[s] * EXP2(ms[s] - M);
        mlq = M + __log2f(L);
    }
    const float4v cinit = {-mlq, -mlq, -mlq, -mlq};

    float4v acc[4][4];                           // [ct][qt]
#pragma unroll
    for (int i = 0; i < 4; ++i)
#pragma unroll
        for (int j = 0; j < 4; ++j) acc[i][j] = (float4v){0.f, 0.f, 0.f, 0.f};

    const int kt0 = b * 256 + kh * 128;          // k-tile base
    const int ch0 = kh * 64;                     // d chunk base
    short8 kfr[8], dfr[4][4];
#pragma unroll
    for (int kt = 0; kt < 8; ++kt)
        kfr[kt] = *(const short8*)&kfp[((size_t)(kt0 + kt)) * 512 + l * 8];
#pragma unroll
    for (int ct = 0; ct < 4; ++ct)
#pragma unroll
        for (int ch = 0; ch < 4; ++ch)
            dfr[ct][ch] = *(const short8*)&dfp[(((size_t)(b * 16 + ct * 4 + w)) * 128 + ch0 + ch) * 512 + l * 8];

    for (int it = 0; it < 16; ++it) {
        const int ib = it & 1;
        const int nit = (it + 1) & 15;
        // ---- scores for q-tile w over TK=128 (C pre-loaded with -mlq) ----
        float4v st[8];
#pragma unroll
        for (int kt = 0; kt < 8; ++kt)
            st[kt] = __builtin_amdgcn_mfma_f32_16x16x32_bf16(kfr[kt], qfrag, cinit, 0, 0, 0);
#pragma unroll
        for (int kt = 0; kt < 8; ++kt)
            kfr[kt] = *(const short8*)&kfp[((size_t)(kt0 + nit * 8 + kt)) * 512 + l * 8];
        // ---- p = exp2(st), pack, swizzled LDS write ----
        const int qrow = w * 16 + lq;
#pragma unroll
        for (int kt = 0; kt < 8; ++kt) {
            float e0 = EXP2(st[kt][0]);
            float e1 = EXP2(st[kt][1]);
            float e2 = EXP2(st[kt][2]);
            float e3 = EXP2(st[kt][3]);
            uint2 pd = {pack2(e0, e1), pack2(e2, e3)};
            int g = (2 * kt + (lg >> 1)) ^ sw;
            *(uint2*)&Pl[ib][qrow * 128 + g * 8 + (lg & 1) * 4] = pd;
        }
        __syncthreads();
        // ---- PV: O[ct][qt] += D * P^T ----
#pragma unroll
        for (int ch = 0; ch < 4; ++ch) {
            short8 bfr[4];
#pragma unroll
            for (int qt = 0; qt < 4; ++qt) {
                int g = (ch * 4 + lg) ^ sw;
                bfr[qt] = *(const short8*)&Pl[ib][(qt * 16 + lq) * 128 + g * 8];
            }
#pragma unroll
            for (int ct = 0; ct < 4; ++ct) {
#pragma unroll
                for (int qt = 0; qt < 4; ++qt)
                    acc[ct][qt] = __builtin_amdgcn_mfma_f32_16x16x32_bf16(dfr[ct][ch], bfr[qt], acc[ct][qt], 0, 0, 0);
                dfr[ct][ch] = *(const short8*)&dfp[(((size_t)(b * 16 + ct * 4 + w)) * 128 + ch0 + nit * 4 + ch) * 512 + l * 8];
            }
        }
    }
    // ---- epilogue: out += partial O (out pre-initialized to x) ----
#pragma unroll
    for (int ct = 0; ct < 4; ++ct)
#pragma unroll
        for (int r = 0; r < 4; ++r) {
            int c = (ct * 4 + w) * 16 + lg * 4 + r;
            size_t base = ((size_t)b * C_ + c) * N_ + n0q;
#pragma unroll
            for (int qt = 0; qt < 4; ++qt) {
                size_t idx = base + qt * 16 + lq;
                unsafeAtomicAdd(&out[idx], acc[ct][qt][r]);
            }
        }
}

extern "C" void kernel_launch(void* const* d_in, const int* in_sizes, int n_in,
                              void* d_out, int out_size, void* d_ws, size_t ws_size,
                              hipStream_t stream) {
    (void)in_sizes; (void)n_in; (void)out_size; (void)ws_size;
    const float* x  = (const float*)d_in[0];
    const float* w1 = (const float*)d_in[1];
    const float* w2 = (const float*)d_in[2];
    const float* w3 = (const float*)d_in[3];
    const float* g1 = (const float*)d_in[4];
    const float* b1 = (const float*)d_in[5];
    const float* g2 = (const float*)d_in[6];
    const float* b2 = (const float*)d_in[7];
    const float* g3 = (const float*)d_in[8];
    const float* b3 = (const float*)d_in[9];
    uint8_t* wsb = (uint8_t*)d_ws;
    float* sums = (float*)(wsb + SUM_OFF_B);
    float* outp = (float*)d_out;

    wsplit_kernel<<<320, 256, 0, stream>>>(w1, w2, w3, wsb);
    initout_kernel<<<4096, 256, 0, stream>>>(x, outp);
    ygemm_kernel<<<512, 256, 0, stream>>>(x, wsb);
    finalize_kernel<<<1, 320, 0, stream>>>(g1, b1, g2, b2, g3, b3, sums);
    affine_kernel<<<2560, 256, 0, stream>>>(wsb);
    mlpass_kernel<<<1024, 256, 0, stream>>>(wsb);
    flash_kernel<<<512, 256, 0, stream>>>(wsb, outp);
}